// Round 4
// baseline (273.988 us; speedup 1.0000x reference)
//
#include <hip/hip_runtime.h>

// RoIBridge: gather sinusoidal positional embeddings per bbox coordinate,
// mask by obj_vec==1, write dense [B*T, 256] fp32 buffer.
// B=2048, T=128, D=64, IMAGE_SIZE=224 (table: 225x64 fp32 = 57.6 KB).
//
// Memory-bound: 268 MB output stream dominates. Design:
//  - wave (64 lanes) covers one 256-float row; 4 rows per wave
//    => 4 independent load->gather->store chains for ILP.
//  - PLAIN stores this round (single-variable experiment vs R3's
//    nontemporal): wave writes 1 KB contiguous = full 64 B lines, so no
//    RFO through L2; harness fills prove this path sustains 6.4 TB/s.
//    nt may de-aggregate into sub-burst HBM writes (RMW penalty).
//  - lanes 0-15 share one bbox coord (broadcast); each 16-lane group reads
//    one contiguous 256 B table row; stores fully coalesced 16 B/lane.

#define ROI_ROWS (2048 * 128)   // B*T = 262,144
#define ROI_IMG  224.0f
#define ROWS_PER_WAVE 4

typedef float vfloat4 __attribute__((ext_vector_type(4)));

__global__ __launch_bounds__(256) void RoIBridge_kernel(
    const float*   __restrict__ bboxs,   // [ROWS*4]
    const int*     __restrict__ objs,    // [ROWS]
    const vfloat4* __restrict__ table,   // [225*16] float4s
    vfloat4*       __restrict__ out)     // [ROWS*64] float4s
{
    const int tid  = blockIdx.x * 256 + threadIdx.x;
    const int wave = tid >> 6;
    const int lane = threadIdx.x & 63;
    const int c    = lane >> 4;        // coord 0..3 (16 lanes each)
    const int d4   = lane & 15;        // float4 within 64-float embedding

    const int row0 = wave * ROWS_PER_WAVE;

    // Phase 1: independent input loads up front
    int   obj[ROWS_PER_WAVE];
    float frac[ROWS_PER_WAVE];
#pragma unroll
    for (int r = 0; r < ROWS_PER_WAVE; ++r) {
        obj[r]  = objs[row0 + r];
        frac[r] = bboxs[((row0 + r) << 2) + c];
    }

    // Phase 2: dependent gathers (4 independent chains in flight)
    vfloat4 e[ROWS_PER_WAVE];
#pragma unroll
    for (int r = 0; r < ROWS_PER_WAVE; ++r) {
        float v = fminf(fmaxf(frac[r] * ROI_IMG, 0.0f), ROI_IMG);
        const int idx = (int)v;            // trunc toward 0
        e[r] = table[idx * 16 + d4];       // 256B/row, coalesced
    }

    // Phase 3: masked plain streaming stores (full-line, no RFO)
    const vfloat4 z = (vfloat4){0.0f, 0.0f, 0.0f, 0.0f};
#pragma unroll
    for (int r = 0; r < ROWS_PER_WAVE; ++r) {
        out[(row0 + r) * 64 + lane] = (obj[r] == 1) ? e[r] : z;
    }
}

extern "C" void kernel_launch(void* const* d_in, const int* in_sizes, int n_in,
                              void* d_out, int out_size, void* d_ws, size_t ws_size,
                              hipStream_t stream) {
    const float*   bboxs = (const float*)d_in[0];   // [2048,128,4] fp32
    const int*     objs  = (const int*)d_in[1];     // [2048,128] int32
    const vfloat4* table = (const vfloat4*)d_in[2]; // [225,64] fp32
    vfloat4* out = (vfloat4*)d_out;                 // [262144*64] float4

    // waves = ROWS/4 = 65,536 ; blocks (4 waves each) = 16,384
    RoIBridge_kernel<<<ROI_ROWS / (ROWS_PER_WAVE * 4), 256, 0, stream>>>(
        bboxs, objs, table, out);
}